// Round 2
// baseline (840.531 us; speedup 1.0000x reference)
//
#include <hip/hip_runtime.h>
#include <math.h>

// ---------------- problem constants (static per setup_inputs) ----------------
#define CC 512
#define HH 8
#define BBATCH 8
#define LMAX 1024
#define NTOK 6144

__constant__ int c_LEN[8] = {512, 640, 768, 896, 1024, 896, 768, 640};
__constant__ int c_OFF[8] = {0, 512, 1152, 1920, 2816, 3840, 4736, 5504};

using bf16x8 = __attribute__((ext_vector_type(8))) short;
using f32x4  = __attribute__((ext_vector_type(4))) float;

__device__ __forceinline__ unsigned short f2bf(float f) {
    union { float f; unsigned u; } v; v.f = f;
    unsigned r = v.u + 0x7fffu + ((v.u >> 16) & 1u);
    return (unsigned short)(r >> 16);
}

// ---------------- small prep kernels ----------------
__global__ __launch_bounds__(256) void cast_bf16_kernel(const float* __restrict__ in,
                                                        unsigned short* __restrict__ out, int n4) {
    int i = blockIdx.x * 256 + threadIdx.x;
    if (i < n4) {
        float4 v = ((const float4*)in)[i];
        ushort4 o;
        o.x = f2bf(v.x); o.y = f2bf(v.y); o.z = f2bf(v.z); o.w = f2bf(v.w);
        ((ushort4*)out)[i] = o;
    }
}

__global__ __launch_bounds__(256) void bn_coef_kernel(
        const float* g1, const float* b1, const float* m1, const float* v1,
        const float* g2, const float* b2, const float* m2, const float* v2,
        float* s1, float* t1, float* s2, float* t2) {
    int c = blockIdx.x * 256 + threadIdx.x;
    if (c >= CC) return;
    float sa = g1[c] * rsqrtf(v1[c] + 1e-5f); s1[c] = sa; t1[c] = b1[c] - m1[c] * sa;
    float sb = g2[c] * rsqrtf(v2[c] + 1e-5f); s2[c] = sb; t2[c] = b2[c] - m2[c] * sb;
}

// BN(features) padded to [B,L,C] in bf16 (zeros for invalid rows)
__global__ __launch_bounds__(256) void xpad_kernel(const float* __restrict__ feat,
        const float* __restrict__ s1, const float* __restrict__ t1,
        unsigned short* __restrict__ xpad) {
    int idx = blockIdx.x * 256 + threadIdx.x;   // 8*1024*64 = 524288
    int c8 = idx & 63, l = (idx >> 6) & 1023, b = idx >> 16;
    union { int4 v; unsigned short u[8]; } st;
    if (l < c_LEN[b]) {
        int row = c_OFF[b] + l;
        const float4* f4 = (const float4*)(feat + (size_t)row * CC + c8 * 8);
        float4 x0 = f4[0], x1 = f4[1];
        const float4* s4 = (const float4*)s1;
        const float4* t4 = (const float4*)t1;
        float4 sa = s4[c8 * 2], sb = s4[c8 * 2 + 1];
        float4 ta = t4[c8 * 2], tb = t4[c8 * 2 + 1];
        st.u[0] = f2bf(x0.x * sa.x + ta.x);
        st.u[1] = f2bf(x0.y * sa.y + ta.y);
        st.u[2] = f2bf(x0.z * sa.z + ta.z);
        st.u[3] = f2bf(x0.w * sa.w + ta.w);
        st.u[4] = f2bf(x1.x * sb.x + tb.x);
        st.u[5] = f2bf(x1.y * sb.y + tb.y);
        st.u[6] = f2bf(x1.z * sb.z + tb.z);
        st.u[7] = f2bf(x1.w * sb.w + tb.w);
    } else {
        st.v = make_int4(0, 0, 0, 0);
    }
    *(int4*)&xpad[(size_t)(b * 1024 + l) * CC + c8 * 8] = st.v;
}

// ---------------- generic bf16 MFMA GEMM: C[m][n] = sum_k A[m][k]*Bw[n][k] ----------------
// MODE 0: QKV  (A=xpad bf16)       -> qpack/kpack (head-packed bf16) + vtmp bf16
// MODE 1: out-proj (A=ctx bf16)    -> d_out = val + bias + features   (unpad + residual)
// MODE 2: FFN1 (A=d_out f32, BN on load via aux0/aux1) -> ffn_h = bf16(gelu(val+bias))
// MODE 3: FFN2 (A=ffn_h bf16)      -> d_out += val + bias
template<int MODE, int KDIM>
__global__ __launch_bounds__(256) void gemm_kernel(
        const void* __restrict__ A, const unsigned short* __restrict__ Bw,
        const float* __restrict__ bias,
        unsigned short* __restrict__ o0, unsigned short* __restrict__ o1,
        unsigned short* __restrict__ o2,
        float* __restrict__ of, const float* __restrict__ aux0, const float* __restrict__ aux1) {
    __shared__ __align__(16) unsigned short As[128 * 72];   // 64 + 8 pad per row
    __shared__ __align__(16) unsigned short Bs[128 * 72];

    const int tid = threadIdx.x;
    const int w = tid >> 6, lane = tid & 63;
    const int wm = w >> 1, wn = w & 1;
    const int lr = lane & 15, lh = lane >> 4;
    const int m0 = blockIdx.x * 128, n0 = blockIdx.y * 128;
    const int srow = tid >> 1, shalf = tid & 1;

    f32x4 acc[4][4];
#pragma unroll
    for (int i = 0; i < 4; ++i)
#pragma unroll
        for (int j = 0; j < 4; ++j)
#pragma unroll
            for (int r = 0; r < 4; ++r) acc[i][j][r] = 0.f;

    for (int kt = 0; kt < KDIM / 64; ++kt) {
        // ---- stage A tile [128][64] ----
        if (MODE == 2) {
            const float* Ap = ((const float*)A) + (size_t)(m0 + srow) * KDIM + kt * 64 + shalf * 32;
            union { int4 v[4]; unsigned short u[32]; } tmp;
#pragma unroll
            for (int j = 0; j < 8; ++j) {
                float4 x = ((const float4*)Ap)[j];
                int cb = (kt * 64 + shalf * 32 + j * 4) >> 2;
                float4 sc = ((const float4*)aux0)[cb];
                float4 tc = ((const float4*)aux1)[cb];
                tmp.u[j * 4 + 0] = f2bf(x.x * sc.x + tc.x);
                tmp.u[j * 4 + 1] = f2bf(x.y * sc.y + tc.y);
                tmp.u[j * 4 + 2] = f2bf(x.z * sc.z + tc.z);
                tmp.u[j * 4 + 3] = f2bf(x.w * sc.w + tc.w);
            }
            int4* dst = (int4*)&As[srow * 72 + shalf * 32];
#pragma unroll
            for (int j = 0; j < 4; ++j) dst[j] = tmp.v[j];
        } else {
            const unsigned short* Ap = ((const unsigned short*)A) + (size_t)(m0 + srow) * KDIM + kt * 64 + shalf * 32;
            int4* dst = (int4*)&As[srow * 72 + shalf * 32];
#pragma unroll
            for (int j = 0; j < 4; ++j) dst[j] = ((const int4*)Ap)[j];
        }
        {
            const unsigned short* Bp = Bw + (size_t)(n0 + srow) * KDIM + kt * 64 + shalf * 32;
            int4* dst = (int4*)&Bs[srow * 72 + shalf * 32];
#pragma unroll
            for (int j = 0; j < 4; ++j) dst[j] = ((const int4*)Bp)[j];
        }
        __syncthreads();
        // ---- compute ----
#pragma unroll
        for (int ks = 0; ks < 2; ++ks) {
            bf16x8 af[4], bfr[4];
#pragma unroll
            for (int i = 0; i < 4; ++i)
                af[i] = *(const bf16x8*)&As[(wm * 64 + i * 16 + lr) * 72 + ks * 32 + lh * 8];
#pragma unroll
            for (int j = 0; j < 4; ++j)
                bfr[j] = *(const bf16x8*)&Bs[(wn * 64 + j * 16 + lr) * 72 + ks * 32 + lh * 8];
#pragma unroll
            for (int i = 0; i < 4; ++i)
#pragma unroll
                for (int j = 0; j < 4; ++j)
                    acc[i][j] = __builtin_amdgcn_mfma_f32_16x16x32_bf16(af[i], bfr[j], acc[i][j], 0, 0, 0);
        }
        __syncthreads();
    }

    // ---- epilogue: D[row][col], col=lane&15, row=(lane>>4)*4+r ----
#pragma unroll
    for (int i = 0; i < 4; ++i)
#pragma unroll
        for (int j = 0; j < 4; ++j) {
            int n = n0 + wn * 64 + j * 16 + lr;
            float bv = bias[n];
#pragma unroll
            for (int r = 0; r < 4; ++r) {
                int m = m0 + wm * 64 + i * 16 + lh * 4 + r;
                float val = acc[i][j][r] + bv;
                if (MODE == 0) {
                    int b = m >> 10, l = m & 1023;
                    unsigned short bf = f2bf(val);
                    int head = (n >> 6) & 7;
                    if (n < 512)
                        o0[((size_t)(b * 8 + head) * 1024 + l) * 64 + (n & 63)] = bf;
                    else if (n < 1024)
                        o1[((size_t)(b * 8 + head) * 1024 + l) * 64 + (n & 63)] = bf;
                    else
                        o2[(size_t)m * 512 + (n - 1024)] = bf;
                } else if (MODE == 1) {
                    int b = m >> 10, l = m & 1023;
                    if (l < c_LEN[b]) {
                        int row = c_OFF[b] + l;
                        of[(size_t)row * 512 + n] = val + aux0[(size_t)row * 512 + n];
                    }
                } else if (MODE == 2) {
                    float g = 0.5f * val * (1.0f + erff(val * 0.70710678118654752f));
                    o0[(size_t)m * 1024 + n] = f2bf(g);
                } else {
                    of[(size_t)m * 512 + n] += val;
                }
            }
        }
}

// ---------------- V transpose: vtmp[B*L][C] -> vT[(b*H+h)*64 + d][L] ----------------
__global__ __launch_bounds__(256) void vtrans_kernel(const unsigned short* __restrict__ vtmp,
                                                     unsigned short* __restrict__ vT) {
    __shared__ __align__(16) unsigned short tile[64][72];
    int bh = blockIdx.x, lt = blockIdx.y;
    int b = bh >> 3, h = bh & 7;
    int t = threadIdx.x;
    int r = t >> 2, cq = t & 3;
    const int4* src = (const int4*)(vtmp + ((size_t)(b * 1024 + lt * 64 + r)) * 512 + h * 64 + cq * 16);
    union { int4 v[2]; unsigned short u[16]; } uu;
    uu.v[0] = src[0]; uu.v[1] = src[1];
#pragma unroll
    for (int i = 0; i < 16; ++i) tile[cq * 16 + i][r] = uu.u[i];
    __syncthreads();
    int d = t >> 2, lq = t & 3;
    int4 q0 = *(const int4*)&tile[d][lq * 16];
    int4 q1 = *(const int4*)&tile[d][lq * 16 + 8];
    int4* dst = (int4*)(vT + ((size_t)(bh * 64 + d)) * 1024 + lt * 64 + lq * 16);
    dst[0] = q0; dst[1] = q1;
}

// ---------------- fused attention: one block per (b, 16-row q tile), loops all 8 heads ----------------
__global__ __launch_bounds__(256, 1) void attn_kernel(
        const unsigned short* __restrict__ qpack, const unsigned short* __restrict__ kpack,
        const unsigned short* __restrict__ vT, const float* __restrict__ rpe,
        unsigned short* __restrict__ ctx, float* __restrict__ awout) {
    __shared__ __align__(16) float S[16][1028];       // padded vs stride-4KB bank conflict
    __shared__ __align__(16) float AW[16][1024];
    __shared__ __align__(16) float CTXP[4][16][68];
    __shared__ __align__(16) float INVL[16];

    const int tid = threadIdx.x;
    const int w = tid >> 6, lane = tid & 63;
    const int lr = lane & 15, lh = lane >> 4;
    const int b = blockIdx.x >> 6, qt = blockIdx.x & 63;
    const int q0 = qt << 4;
    const int len = c_LEN[b];

    for (int i = tid; i < 16 * 1024; i += 256) ((float*)AW)[i] = 0.f;
    __syncthreads();

    for (int h = 0; h < 8; ++h) {
        const unsigned short* qbase = qpack + ((size_t)((b * 8 + h) * 1024 + q0)) * 64;
        const unsigned short* kbase = kpack + ((size_t)((b * 8 + h) * 1024)) * 64;
        const float* rpb = rpe + ((size_t)(b * 8 + h)) * 1024 * 1024 + (size_t)q0 * 1024;

        bf16x8 aq0 = *(const bf16x8*)&qbase[lr * 64 + lh * 8];
        bf16x8 aq1 = *(const bf16x8*)&qbase[lr * 64 + 32 + lh * 8];

        // phase 1: S = QK^T * 0.125 + rpe (+mask), this wave owns cols [w*256, w*256+256)
        for (int ksub = 0; ksub < 16; ++ksub) {
            int kcb = w * 256 + ksub * 16;
            f32x4 acc; acc[0] = acc[1] = acc[2] = acc[3] = 0.f;
            bf16x8 bk0 = *(const bf16x8*)&kbase[(size_t)(kcb + lr) * 64 + lh * 8];
            bf16x8 bk1 = *(const bf16x8*)&kbase[(size_t)(kcb + lr) * 64 + 32 + lh * 8];
            acc = __builtin_amdgcn_mfma_f32_16x16x32_bf16(aq0, bk0, acc, 0, 0, 0);
            acc = __builtin_amdgcn_mfma_f32_16x16x32_bf16(aq1, bk1, acc, 0, 0, 0);
            int kk = kcb + lr;
            if (kk >= len) {
#pragma unroll
                for (int r = 0; r < 4; ++r) S[lh * 4 + r][kk] = -1e30f;
            } else {
#pragma unroll
                for (int r = 0; r < 4; ++r) {
                    int qi = lh * 4 + r;
                    S[qi][kk] = acc[r] * 0.125f + rpb[qi * 1024 + kk];
                }
            }
        }
        __syncthreads();

        // phase 2: softmax on rows w*4..w*4+3 (f32), accumulate attn_w mean
#pragma unroll
        for (int rr = 0; rr < 4; ++rr) {
            int qi = w * 4 + rr;
            float* srow = S[qi];
            float mx = -1e30f;
            for (int c = lane; c < 1024; c += 64) mx = fmaxf(mx, srow[c]);
#pragma unroll
            for (int off = 32; off; off >>= 1) mx = fmaxf(mx, __shfl_xor(mx, off));
            float sum = 0.f;
#pragma unroll
            for (int c4 = 0; c4 < 4; ++c4) {
                f32x4 v = *(f32x4*)&srow[lane * 4 + c4 * 256];
#pragma unroll
                for (int i = 0; i < 4; ++i) { float p = __expf(v[i] - mx); v[i] = p; sum += p; }
                *(f32x4*)&srow[lane * 4 + c4 * 256] = v;
            }
#pragma unroll
            for (int off = 32; off; off >>= 1) sum += __shfl_xor(sum, off);
            float il = 1.f / sum;
            if (lane == 0) INVL[qi] = il;
            float sc = il * 0.125f;   // 1/sum * 1/H
#pragma unroll
            for (int c4 = 0; c4 < 4; ++c4) {
                f32x4 p = *(f32x4*)&srow[lane * 4 + c4 * 256];
                f32x4 a = *(f32x4*)&AW[qi][lane * 4 + c4 * 256];
#pragma unroll
                for (int i = 0; i < 4; ++i) a[i] += p[i] * sc;
                *(f32x4*)&AW[qi][lane * 4 + c4 * 256] = a;
            }
        }
        __syncthreads();

        // phase 3: PV, wave reduces k in [w*256, w*256+256)
        {
            const unsigned short* vbase = vT + ((size_t)(b * 8 + h)) * 64 * 1024;
            f32x4 pacc[4];
#pragma unroll
            for (int d = 0; d < 4; ++d)
#pragma unroll
                for (int r = 0; r < 4; ++r) pacc[d][r] = 0.f;
            for (int ks = 0; ks < 8; ++ks) {
                int kb = w * 256 + ks * 32;
                const float* ps = &S[lr][kb + lh * 8];
                f32x4 p0 = *(const f32x4*)ps;
                f32x4 p1 = *(const f32x4*)(ps + 4);
                union { unsigned short u[8]; bf16x8 v; } ap;
#pragma unroll
                for (int i = 0; i < 4; ++i) { ap.u[i] = f2bf(p0[i]); ap.u[4 + i] = f2bf(p1[i]); }
#pragma unroll
                for (int d = 0; d < 4; ++d) {
                    bf16x8 bv = *(const bf16x8*)&vbase[(size_t)(d * 16 + lr) * 1024 + kb + lh * 8];
                    pacc[d] = __builtin_amdgcn_mfma_f32_16x16x32_bf16(ap.v, bv, pacc[d], 0, 0, 0);
                }
            }
#pragma unroll
            for (int d = 0; d < 4; ++d)
#pragma unroll
                for (int r = 0; r < 4; ++r) {
                    int qi = lh * 4 + r;
                    CTXP[w][qi][d * 16 + lr] = pacc[d][r] * INVL[qi];
                }
        }
        __syncthreads();

        // phase 4: reduce partials, write ctx (bf16)
        {
            int qi = tid >> 4, d0 = (tid & 15) * 4;
            float o[4];
#pragma unroll
            for (int dd = 0; dd < 4; ++dd)
                o[dd] = CTXP[0][qi][d0 + dd] + CTXP[1][qi][d0 + dd] + CTXP[2][qi][d0 + dd] + CTXP[3][qi][d0 + dd];
            unsigned short* cdst = ctx + ((size_t)(b * 1024 + q0 + qi)) * 512 + h * 64 + d0;
            ushort4 ov; ov.x = f2bf(o[0]); ov.y = f2bf(o[1]); ov.z = f2bf(o[2]); ov.w = f2bf(o[3]);
            *(ushort4*)cdst = ov;
        }
        __syncthreads();
    }

    // write attn_w rows (this wave owns rows w*4..w*4+3)
#pragma unroll
    for (int rr = 0; rr < 4; ++rr) {
        int qi = w * 4 + rr;
        float* dst = awout + ((size_t)(b * 1024 + q0 + qi)) * 1024;
#pragma unroll
        for (int c4 = 0; c4 < 4; ++c4) {
            f32x4 v = *(f32x4*)&AW[qi][lane * 4 + c4 * 256];
            *(f32x4*)&dst[lane * 4 + c4 * 256] = v;
        }
    }
}

// ---------------- host launcher ----------------
extern "C" void kernel_launch(void* const* d_in, const int* in_sizes, int n_in,
                              void* d_out, int out_size, void* d_ws, size_t ws_size,
                              hipStream_t stream) {
    (void)in_sizes; (void)n_in; (void)out_size; (void)ws_size;
    const float* features = (const float*)d_in[0];
    const float* rpe      = (const float*)d_in[3];
    const float* ng = (const float*)d_in[4];  const float* nbeta = (const float*)d_in[5];
    const float* nm = (const float*)d_in[6];  const float* nv = (const float*)d_in[7];
    const float* Wq = (const float*)d_in[8];  const float* bq = (const float*)d_in[9];
    const float* Wo = (const float*)d_in[10]; const float* bo = (const float*)d_in[11];
    const float* fg = (const float*)d_in[12]; const float* fb = (const float*)d_in[13];
    const float* fm = (const float*)d_in[14]; const float* fv = (const float*)d_in[15];
    const float* W1 = (const float*)d_in[16]; const float* b1 = (const float*)d_in[17];
    const float* W2 = (const float*)d_in[18]; const float* b2 = (const float*)d_in[19];

    char* ws = (char*)d_ws;
    size_t off = 0;
    auto alloc = [&](size_t bytes) -> char* {
        char* p = ws + off; off += (bytes + 255) & ~(size_t)255; return p;
    };
    unsigned short* xpad  = (unsigned short*)alloc((size_t)8192 * 512 * 2);
    unsigned short* qpack = (unsigned short*)alloc((size_t)8 * 8 * 1024 * 64 * 2);
    unsigned short* kpack = (unsigned short*)alloc((size_t)8 * 8 * 1024 * 64 * 2);
    unsigned short* vtmp  = (unsigned short*)alloc((size_t)8192 * 512 * 2);
    unsigned short* vTb   = (unsigned short*)alloc((size_t)8 * 8 * 64 * 1024 * 2);
    unsigned short* ctx   = (unsigned short*)alloc((size_t)8192 * 512 * 2);
    unsigned short* Wqb   = (unsigned short*)alloc((size_t)1536 * 512 * 2);
    unsigned short* Wob   = (unsigned short*)alloc((size_t)512 * 512 * 2);
    unsigned short* W1b   = (unsigned short*)alloc((size_t)1024 * 512 * 2);
    unsigned short* W2b   = (unsigned short*)alloc((size_t)512 * 1024 * 2);
    float* s1 = (float*)alloc(512 * 4);
    float* t1 = (float*)alloc(512 * 4);
    float* s2 = (float*)alloc(512 * 4);
    float* t2 = (float*)alloc(512 * 4);
    // ffn_h aliases xpad+qpack (both dead by the time FFN1 runs)
    unsigned short* ffn_h = xpad;

    float* out0 = (float*)d_out;                    // [6144, 512]
    float* aw   = out0 + (size_t)6144 * 512;        // [8, 1024, 1024]

    // weight casts
    cast_bf16_kernel<<<(1536 * 512 / 4 + 255) / 256, 256, 0, stream>>>(Wq, Wqb, 1536 * 512 / 4);
    cast_bf16_kernel<<<(512 * 512 / 4 + 255) / 256, 256, 0, stream>>>(Wo, Wob, 512 * 512 / 4);
    cast_bf16_kernel<<<(1024 * 512 / 4 + 255) / 256, 256, 0, stream>>>(W1, W1b, 1024 * 512 / 4);
    cast_bf16_kernel<<<(512 * 1024 / 4 + 255) / 256, 256, 0, stream>>>(W2, W2b, 512 * 1024 / 4);
    bn_coef_kernel<<<2, 256, 0, stream>>>(ng, nbeta, nm, nv, fg, fb, fm, fv, s1, t1, s2, t2);
    xpad_kernel<<<524288 / 256, 256, 0, stream>>>(features, s1, t1, xpad);

    // QKV projection -> head-packed q/k + v
    gemm_kernel<0, 512><<<dim3(64, 12), 256, 0, stream>>>(xpad, Wqb, bq, qpack, kpack, vtmp,
                                                          nullptr, nullptr, nullptr);
    vtrans_kernel<<<dim3(64, 16), 256, 0, stream>>>(vtmp, vTb);

    // fused attention (scores f32 + rpe + mask, softmax f32, attn_w mean, PV)
    attn_kernel<<<512, 256, 0, stream>>>(qpack, kpack, vTb, rpe, ctx, aw);

    // out-proj + residual + unpad -> d_out
    gemm_kernel<1, 512><<<dim3(64, 4), 256, 0, stream>>>(ctx, Wob, bo, nullptr, nullptr, nullptr,
                                                         out0, features, nullptr);
    // FFN1 (BN fused on load) + exact GELU
    gemm_kernel<2, 512><<<dim3(48, 8), 256, 0, stream>>>(out0, W1b, b1, ffn_h, nullptr, nullptr,
                                                         nullptr, s2, t2);
    // FFN2, accumulate into d_out
    gemm_kernel<3, 1024><<<dim3(48, 4), 256, 0, stream>>>(ffn_h, W2b, b2, nullptr, nullptr, nullptr,
                                                          out0, nullptr, nullptr);
}